// Round 5
// baseline (175.645 us; speedup 1.0000x reference)
//
#include <hip/hip_runtime.h>
#include <hip/hip_bf16.h>
#include <hip/hip_fp16.h>

// N=4096 nodes, E=4096 hyperedges, F=256, H=256. All float tensors f32;
// batch_mask int32. out = 8192 f32: [pos_score | neg_score].
//
// R5: replace the full per-column radix SORT (~28 us) with radix-SELECT
// (top-64 / bot-64 only):
//   - 4 nibble-counting rounds find the exact 64th-largest / 64th-smallest
//     VALUE threshold (counts only: no scatter, no 8192-entry scan,
//     no key movement; keys stay in registers)
//   - ties at the threshold are interchangeable (reference reduces VALUES;
//     equal values give identical max/min), so any (64-A) tie keys work
//   - block prefix-scan compacts definites+ties; one wave bitonic-sorts
//     each 64-list (21 shfl_xor stages) -> same topkG/botkG interface
//   - LDS 52 KB -> ~9 KB; mask bitmap pack stays fused (the 64-MB mask
//     stream now BOUNDS the kernel at ~10 us instead of riding free)

typedef short bf16x8 __attribute__((ext_vector_type(8)));
typedef float f32x4 __attribute__((ext_vector_type(4)));
typedef short s16x2 __attribute__((ext_vector_type(2)));
typedef unsigned short u16x2 __attribute__((ext_vector_type(2)));

static __device__ __forceinline__ unsigned short f2bf(float f) {
    __hip_bfloat16 b = __float2bfloat16(f);
    return __builtin_bit_cast(unsigned short, b);
}
static __device__ __forceinline__ float f16u_to_f(unsigned u) {
    __half h = __builtin_bit_cast(__half, (unsigned short)(u & 0xffffu));
    return __half2float(h);
}
static __device__ __forceinline__ unsigned pkmax_i16(unsigned a, unsigned b) {
    s16x2 r = __builtin_elementwise_max(__builtin_bit_cast(s16x2, a), __builtin_bit_cast(s16x2, b));
    return __builtin_bit_cast(unsigned, r);
}
static __device__ __forceinline__ unsigned pkmin_u16(unsigned a, unsigned b) {
    u16x2 r = __builtin_elementwise_min(__builtin_bit_cast(u16x2, a), __builtin_bit_cast(u16x2, b));
    return __builtin_bit_cast(unsigned, r);
}

// ---------------------------------------------------------------- tiny W transpose
// Wt[n][k] = bf16(W[k][n]) for both weight matrices. grid (4,4,2), 256 thr.
__global__ void k_prepW(const float* __restrict__ Ws, const float* __restrict__ Wh,
                        unsigned short* __restrict__ Wts, unsigned short* __restrict__ Wth) {
    __shared__ unsigned short tile[64][65];
    const int k0 = blockIdx.x * 64, n0 = blockIdx.y * 64;
    const float* W     = blockIdx.z ? Wh : Ws;
    unsigned short* Wt = blockIdx.z ? Wth : Wts;
    const int t = threadIdx.x;
#pragma unroll
    for (int m = 0; m < 16; m++) {
        int li = t + m * 256; int r = li >> 6, c = li & 63;
        tile[r][c] = f2bf(W[(size_t)(k0 + r) * 256 + n0 + c]);
    }
    __syncthreads();
#pragma unroll
    for (int m = 0; m < 16; m++) {
        int li = t + m * 256; int c2 = li >> 6, r2 = li & 63;
        Wt[(size_t)(n0 + c2) * 256 + k0 + r2] = tile[r2][c2];
    }
}

// ---------------------------------------------------------------- standalone mask pack (fallback path only)
__global__ void k_pack(const int* __restrict__ mask, unsigned* __restrict__ packed) {
    const int w = blockIdx.x * 256 + threadIdx.x;
    const int* p = mask + (size_t)w * 32;
    unsigned word = 0;
#pragma unroll
    for (int j = 0; j < 32; j += 4) {
        int4 m = *(const int4*)(p + j);
        word |= (m.x != 0 ? (1u << (31 - j)) : 0u)
              | (m.y != 0 ? (1u << (30 - j)) : 0u)
              | (m.z != 0 ? (1u << (29 - j)) : 0u)
              | (m.w != 0 ? (1u << (28 - j)) : 0u);
    }
    packed[w] = word;
}

// ---------------------------------------------------------------- GEMM + relu -> f16 h
// tmode=1: write hOut TRANSPOSED as hT[br][c][r]  (main path; feeds k_select)
// tmode=0: write hOut row-major   as h [br][r][c] (fallback path; feeds k_pool9)
__launch_bounds__(256)
__global__ void k_gemm_relu(const float* __restrict__ pXf, const float* __restrict__ pXm,
                            const float* __restrict__ nXf, const float* __restrict__ nXm,
                            const unsigned short* __restrict__ Wts, const unsigned short* __restrict__ Wth,
                            const float* __restrict__ bs,  const float* __restrict__ bh,
                            unsigned short* __restrict__ hOut, int tmode) {
    const int t  = threadIdx.x;
    const int wv = t >> 6;
    const int l  = t & 63;
    const int lm = l & 15;
    const int q  = l >> 4;
    const int bz = blockIdx.z;
    const float* Xf = bz ? nXf : pXf;
    const float* Xm = bz ? nXm : pXm;
    unsigned short* hb = hOut + (size_t)bz * 4096 * 256;

    const int m0 = blockIdx.x * 64 + wv * 16;
    const int n0 = blockIdx.y * 64;

    f32x4 acc[4] = {};
#pragma unroll
    for (int ks = 0; ks < 512; ks += 32) {
        const float* X           = (ks < 256) ? Xf : Xm;
        const unsigned short* Wt = (ks < 256) ? Wts : Wth;
        const int kk = (ks & 255) + q * 8;
        float4 a0 = *(const float4*)(X + (m0 + lm) * 256 + kk);
        float4 a1 = *(const float4*)(X + (m0 + lm) * 256 + kk + 4);
        bf16x8 a;
        a[0] = (short)f2bf(a0.x); a[1] = (short)f2bf(a0.y);
        a[2] = (short)f2bf(a0.z); a[3] = (short)f2bf(a0.w);
        a[4] = (short)f2bf(a1.x); a[5] = (short)f2bf(a1.y);
        a[6] = (short)f2bf(a1.z); a[7] = (short)f2bf(a1.w);
#pragma unroll
        for (int nt = 0; nt < 4; nt++) {
            bf16x8 b = *(const bf16x8*)(Wt + (n0 + nt * 16 + lm) * 256 + kk);
            acc[nt] = __builtin_amdgcn_mfma_f32_16x16x32_bf16(a, b, acc[nt], 0, 0, 0);
        }
    }
    if (tmode) {
#pragma unroll
        for (int nt = 0; nt < 4; nt++) {
            const int c = n0 + nt * 16 + lm;
            const float bsum = bs[c] + bh[c];
            ushort4 v4;
#pragma unroll
            for (int i = 0; i < 4; i++) {
                float v = acc[nt][i] + bsum;
                v = v > 0.f ? v : 0.f;   // relu => h >= +0.0 (u16-monotonic f16 bits)
                ((unsigned short*)&v4)[i] = __builtin_bit_cast(unsigned short, __float2half(v));
            }
            *(ushort4*)(hb + (size_t)c * 4096 + m0 + q * 4) = v4;
        }
    } else {
#pragma unroll
        for (int nt = 0; nt < 4; nt++) {
            const int c = n0 + nt * 16 + lm;
            const float bsum = bs[c] + bh[c];
#pragma unroll
            for (int i = 0; i < 4; i++) {
                const int r = m0 + q * 4 + i;
                float v = acc[nt][i] + bsum;
                v = v > 0.f ? v : 0.f;
                hb[(size_t)r * 256 + c] = __builtin_bit_cast(unsigned short, __float2half(v));
            }
        }
    }
}

// ---------------------------------------------------------------- radix-SELECT top/bot-64 + mask pack
// One block per (col, branch), 512 threads, 8 values/thread (registers).
// 4 nibble rounds refine the exact 64th-value threshold for top (desc) and
// bot (asc) chains simultaneously. Per round: per-thread nibble-packed
// counts -> LDS -> 4 reducer waves (u8/u16 field expansion + shfl tree) ->
// thread 0 picks the boundary bin. Compaction: block prefix-scan over
// (defCnt | tieCnt<<16); ties beyond (64-A) dropped (equal values are
// interchangeable for max/min). One wave bitonic-sorts each 64-list by
// full key (complement trick for descending). Mask pack fused as before.
// LDS ~9.3 KB. grid (256, 2), block 512.
__launch_bounds__(512)
__global__ void k_select(const unsigned short* __restrict__ hT,
                         const int* __restrict__ mask,
                         unsigned* __restrict__ packed,
                         unsigned* __restrict__ topkG, unsigned* __restrict__ botkG) {
    __shared__ unsigned cbuf[4][512];     // [T-lo, T-hi, B-lo, B-hi] nibble-packed counts
    __shared__ unsigned totals[4][4];     // per-reducer-wave: 8 u16 totals in 4 u32
    __shared__ unsigned selS[4];          // prefT, needT, prefB, needB
    __shared__ unsigned aS[2];            // A_top, A_bot (= #definites)
    __shared__ unsigned wtot2[8][2];      // compaction scan wave totals
    __shared__ unsigned top64[64], bot64[64];

    const int c = blockIdx.x, br = blockIdx.y, t = threadIdx.x;
    const int wv = t >> 6, l = t & 63;
    const unsigned short* src = hT + (size_t)(br * 256 + c) * 4096;

    // mask pack: thread owns packed words 2*gt, 2*gt+1
    const int gt = (br * 256 + c) * 512 + t;
    const int4* mp = (const int4*)(mask + (size_t)gt * 64);
    int4 mr[8];
#pragma unroll
    for (int i = 0; i < 8; i++) mr[i] = mp[i];           // batch 0

    // load 8 consecutive f16 values (u16) into registers
    unsigned vt[8];
    {
        uint4 a = ((const uint4*)src)[t];
        vt[0] = a.x & 0xFFFFu; vt[1] = a.x >> 16;
        vt[2] = a.y & 0xFFFFu; vt[3] = a.y >> 16;
        vt[4] = a.z & 0xFFFFu; vt[5] = a.z >> 16;
        vt[6] = a.w & 0xFFFFu; vt[7] = a.w >> 16;
    }

    auto cvt = [&]() -> unsigned {
        unsigned word = 0;
#pragma unroll
        for (int j2 = 0; j2 < 8; j2++) {
            int4 v = mr[j2];
            const int j = j2 * 4;
            word |= (v.x != 0 ? (1u << (31 - j)) : 0u)
                  | (v.y != 0 ? (1u << (30 - j)) : 0u)
                  | (v.z != 0 ? (1u << (29 - j)) : 0u)
                  | (v.w != 0 ? (1u << (28 - j)) : 0u);
        }
        return word;
    };
    const unsigned pw0 = cvt();                           // batch 0 (arrived under value load)
#pragma unroll
    for (int i = 0; i < 8; i++) mr[i] = mp[8 + i];        // issue batch 1

    // ---- 4 selection rounds (nibbles r=3..0), top & bot chains together
    unsigned prefT = 0, needT = 64, prefB = 0, needB = 64;
#pragma unroll 1
    for (int r = 3; r >= 0; r--) {
        const int shp = (r + 1) * 4, shd = r * 4;
        unsigned cT0 = 0, cT1 = 0, cB0 = 0, cB1 = 0;
#pragma unroll
        for (int m = 0; m < 8; m++) {
            const unsigned hi = vt[m] >> shp;             // r=3: 0 for all (vt<=0xFFFF)
            const unsigned d  = (vt[m] >> shd) & 15u;
            const unsigned inc = 1u << ((d & 7u) * 4);
            const bool lo8 = d < 8u;
            if (hi == prefT) { if (lo8) cT0 += inc; else cT1 += inc; }
            if (hi == prefB) { if (lo8) cB0 += inc; else cB1 += inc; }
        }
        cbuf[0][t] = cT0; cbuf[1][t] = cT1; cbuf[2][t] = cB0; cbuf[3][t] = cB1;
        __syncthreads();

        if (wv < 4) {                                     // reducer wave per count array
            const unsigned* p = cbuf[wv];
            unsigned e0 = 0, e1 = 0;
#pragma unroll
            for (int j = 0; j < 8; j++) {                 // 8 threads' counts -> u8 fields (<=64)
                unsigned x = p[l * 8 + j];
                e0 += x & 0x0F0F0F0Fu;                    // bins 0,2,4,6 (of this half)
                e1 += (x >> 4) & 0x0F0F0F0Fu;             // bins 1,3,5,7
            }
            unsigned w00 = e0 & 0x00FF00FFu, w01 = (e0 >> 8) & 0x00FF00FFu;  // {0,4} {2,6}
            unsigned w10 = e1 & 0x00FF00FFu, w11 = (e1 >> 8) & 0x00FF00FFu;  // {1,5} {3,7}
#pragma unroll
            for (int off = 1; off < 64; off <<= 1) {      // u16 fields, block sums <=4096
                w00 += __shfl_xor(w00, off); w01 += __shfl_xor(w01, off);
                w10 += __shfl_xor(w10, off); w11 += __shfl_xor(w11, off);
            }
            if (l == 0) { totals[wv][0] = w00; totals[wv][1] = w01; totals[wv][2] = w10; totals[wv][3] = w11; }
        }
        __syncthreads();

        if (t == 0) {
            unsigned cnt[16];
            // ---- TOP chain (totals[0]=bins0-7, totals[1]=bins8-15)
            cnt[0]  = totals[0][0] & 0xFFFFu; cnt[4]  = totals[0][0] >> 16;
            cnt[2]  = totals[0][1] & 0xFFFFu; cnt[6]  = totals[0][1] >> 16;
            cnt[1]  = totals[0][2] & 0xFFFFu; cnt[5]  = totals[0][2] >> 16;
            cnt[3]  = totals[0][3] & 0xFFFFu; cnt[7]  = totals[0][3] >> 16;
            cnt[8]  = totals[1][0] & 0xFFFFu; cnt[12] = totals[1][0] >> 16;
            cnt[10] = totals[1][1] & 0xFFFFu; cnt[14] = totals[1][1] >> 16;
            cnt[9]  = totals[1][2] & 0xFFFFu; cnt[13] = totals[1][2] >> 16;
            cnt[11] = totals[1][3] & 0xFFFFu; cnt[15] = totals[1][3] >> 16;
            {
                unsigned S = 0, g = 0, nn = 0; bool done = false;
#pragma unroll
                for (int b = 15; b >= 0; b--) {
                    if (!done) {
                        unsigned cb = cnt[b];
                        if (S + cb >= needT) { g = (unsigned)b; nn = needT - S; done = true; }
                        else S += cb;
                    }
                }
                selS[0] = (prefT << 4) | g; selS[1] = nn;
                if (r == 0) aS[0] = 64u - nn;
            }
            // ---- BOT chain (totals[2], totals[3]), ascending
            cnt[0]  = totals[2][0] & 0xFFFFu; cnt[4]  = totals[2][0] >> 16;
            cnt[2]  = totals[2][1] & 0xFFFFu; cnt[6]  = totals[2][1] >> 16;
            cnt[1]  = totals[2][2] & 0xFFFFu; cnt[5]  = totals[2][2] >> 16;
            cnt[3]  = totals[2][3] & 0xFFFFu; cnt[7]  = totals[2][3] >> 16;
            cnt[8]  = totals[3][0] & 0xFFFFu; cnt[12] = totals[3][0] >> 16;
            cnt[10] = totals[3][1] & 0xFFFFu; cnt[14] = totals[3][1] >> 16;
            cnt[9]  = totals[3][2] & 0xFFFFu; cnt[13] = totals[3][2] >> 16;
            cnt[11] = totals[3][3] & 0xFFFFu; cnt[15] = totals[3][3] >> 16;
            {
                unsigned S = 0, g = 0, nn = 0; bool done = false;
#pragma unroll
                for (int b = 0; b < 16; b++) {
                    if (!done) {
                        unsigned cb = cnt[b];
                        if (S + cb >= needB) { g = (unsigned)b; nn = needB - S; done = true; }
                        else S += cb;
                    }
                }
                selS[2] = (prefB << 4) | g; selS[3] = nn;
                if (r == 0) aS[1] = 64u - nn;
            }
        }
        __syncthreads();
        prefT = selS[0]; needT = selS[1]; prefB = selS[2]; needB = selS[3];
    }

    const unsigned pw1 = cvt();                           // batch 1 (long arrived)

    // ---- compaction: definites (exact) + ties (any 64-A of them)
    const unsigned TvT = prefT, TvB = prefB;
    const unsigned A_T = aS[0], A_B = aS[1];
    unsigned dT = 0, tT = 0, dB = 0, tB = 0;
#pragma unroll
    for (int m = 0; m < 8; m++) {
        dT += vt[m] > TvT;  tT += vt[m] == TvT;
        dB += vt[m] < TvB;  tB += vt[m] == TvB;
    }
    unsigned pkT = dT | (tT << 16), pkB = dB | (tB << 16);
    unsigned sT = pkT, sB = pkB;
#pragma unroll
    for (int off = 1; off < 64; off <<= 1) {              // inclusive wave scan
        unsigned nT = __shfl_up(sT, off), nB = __shfl_up(sB, off);
        if (l >= off) { sT += nT; sB += nB; }
    }
    if (l == 63) { wtot2[wv][0] = sT; wtot2[wv][1] = sB; }
    __syncthreads();
    unsigned exT = sT - pkT, exB = sB - pkB;              // exclusive within wave
#pragma unroll
    for (int w = 0; w < 7; w++)
        if (w < wv) { exT += wtot2[w][0]; exB += wtot2[w][1]; }
    unsigned posDT = exT & 0xFFFFu, posTT = exT >> 16;
    unsigned posDB = exB & 0xFFFFu, posTB = exB >> 16;
#pragma unroll
    for (int m = 0; m < 8; m++) {
        const unsigned key = (vt[m] << 16) | (unsigned)(t * 8 + m);
        if (vt[m] > TvT)        top64[posDT++] = key;
        else if (vt[m] == TvT) { unsigned s2 = A_T + posTT++; if (s2 < 64u) top64[s2] = key; }
        if (vt[m] < TvB)        bot64[posDB++] = key;
        else if (vt[m] == TvB) { unsigned s2 = A_B + posTB++; if (s2 < 64u) bot64[s2] = key; }
    }
    __syncthreads();

    // ---- one-wave bitonic sort of each 64-list (full 32-bit key)
    if (wv < 2) {
        const unsigned flip = (wv == 0) ? 0xFFFFFFFFu : 0u;   // top: sort ~key asc == key desc
        unsigned v = ((wv == 0) ? top64[l] : bot64[l]) ^ flip;
#pragma unroll
        for (unsigned k2 = 2; k2 <= 64; k2 <<= 1) {
#pragma unroll
            for (unsigned j = k2 >> 1; j > 0; j >>= 1) {
                unsigned o = __shfl_xor(v, (int)j);
                const bool keepMin = (((unsigned)l & j) == 0) == (((unsigned)l & k2) == 0);
                const unsigned mn = v < o ? v : o, mx = v < o ? o : v;
                v = keepMin ? mn : mx;
            }
        }
        v ^= flip;
        if (wv == 0) topkG[(br * 64 + l) * 256 + c] = v;
        else         botkG[(br * 64 + l) * 256 + c] = v;
    }

    *(uint2*)(packed + (size_t)gt * 2) = make_uint2(pw0, pw1);
}

// ---------------------------------------------------------------- probe + score
// Block: 16 edges x one branch; 4 waves x 4 edges. Lane l covers cols
// c = l + 64*sl. Probes batched 8-WIDE. Depth 0..15 from LDS; depth 16..63
// from global top/bot-64 (P(reach)=2^-16 per probe); beyond that (P=2^-64)
// an exact direct scan of the hT column keeps correctness unconditional.
// LDS 40 KB. grid (256, 2), block 256.
__launch_bounds__(256)
__global__ void k_probe(const unsigned* __restrict__ topkG,
                        const unsigned* __restrict__ botkG,
                        const unsigned* __restrict__ packed,
                        const unsigned short* __restrict__ hT,
                        const float* __restrict__ Wscore,
                        const float* __restrict__ bscore,
                        float* __restrict__ out) {
    __shared__ __align__(16) unsigned topkL[16 * 256];   // [p][c] 16 KB
    __shared__ __align__(16) unsigned botkL[16 * 256];   // [p][c] 16 KB
    __shared__ __align__(16) unsigned bitsL[16 * 128];   // 8 KB

    const int t  = threadIdx.x;
    const int wv = t >> 6;
    const int l  = t & 63;
    const int e0 = blockIdx.x * 16;
    const int br = blockIdx.y;

    {
        const uint4* ts  = (const uint4*)(topkG + br * 16384);
        const uint4* bs2 = (const uint4*)(botkG + br * 16384);
#pragma unroll
        for (int m = 0; m < 4; m++) {
            ((uint4*)topkL)[t + m * 256] = ts[t + m * 256];
            ((uint4*)botkL)[t + m * 256] = bs2[t + m * 256];
        }
        ((uint4*)bitsL)[t]       = ((const uint4*)(packed + e0 * 128))[t];
        ((uint4*)bitsL)[t + 256] = ((const uint4*)(packed + e0 * 128))[t + 256];
    }
    __syncthreads();

    const float bsc = *bscore;
    float wsv[4];
#pragma unroll
    for (int sl = 0; sl < 4; sl++) wsv[sl] = Wscore[l + 64 * sl];

#pragma unroll 1
    for (int k = 0; k < 4; k++) {
        const int e = wv * 4 + k;
        const unsigned* mk = &bitsL[e * 128];
        float s = 0.f;
#pragma unroll
        for (int sl = 0; sl < 4; sl++) {
            const int c = l + 64 * sl;

            // ---- MAX: first member in descending order
            unsigned sel = 0xFFFFFFFFu;   // > any real key (value<=0x7C00)
#pragma unroll 1
            for (int g = 0; g < 2; g++) {
                unsigned kk[8]; int ss[8];
#pragma unroll
                for (int j = 0; j < 8; j++) kk[j] = topkL[(g * 8 + j) * 256 + c];
#pragma unroll
                for (int j = 0; j < 8; j++)
                    ss[j] = (int)(mk[(kk[j] & 4095u) >> 5] << (kk[j] & 31u));
                unsigned fnd = 0xFFFFFFFFu;
#pragma unroll
                for (int j = 7; j >= 0; j--) if (ss[j] < 0) fnd = kk[j];
                if (fnd != 0xFFFFFFFFu) { sel = fnd; break; }
            }
            if (sel == 0xFFFFFFFFu) {
                const unsigned* tg = topkG + br * 16384 + c;
#pragma unroll 1
                for (int p = 16; p < 64; p++) {
                    unsigned key = tg[p * 256];
                    if ((int)(mk[(key & 4095u) >> 5] << (key & 31u)) < 0) { sel = key; break; }
                }
            }
            if (sel == 0xFFFFFFFFu) {   // exact net (P=2^-64; edge nonempty via diagonal)
                const unsigned short* col = hT + (size_t)(br * 256 + c) * 4096;
                unsigned best = 0;
#pragma unroll 1
                for (int n = 0; n < 4096; n++)
                    if ((int)(mk[n >> 5] << (n & 31)) < 0) { unsigned v = col[n]; if (v > best) best = v; }
                sel = best << 16;
            }
            const float vmax = f16u_to_f(sel >> 16);

            // ---- MIN: first member in ascending order
            sel = 0xFFFFFFFFu;
#pragma unroll 1
            for (int g = 0; g < 2; g++) {
                unsigned kk[8]; int ss[8];
#pragma unroll
                for (int j = 0; j < 8; j++) kk[j] = botkL[(g * 8 + j) * 256 + c];
#pragma unroll
                for (int j = 0; j < 8; j++)
                    ss[j] = (int)(mk[(kk[j] & 4095u) >> 5] << (kk[j] & 31u));
                unsigned fnd = 0xFFFFFFFFu;
#pragma unroll
                for (int j = 7; j >= 0; j--) if (ss[j] < 0) fnd = kk[j];
                if (fnd != 0xFFFFFFFFu) { sel = fnd; break; }
            }
            if (sel == 0xFFFFFFFFu) {
                const unsigned* bg = botkG + br * 16384 + c;
#pragma unroll 1
                for (int p = 16; p < 64; p++) {
                    unsigned key = bg[p * 256];
                    if ((int)(mk[(key & 4095u) >> 5] << (key & 31u)) < 0) { sel = key; break; }
                }
            }
            if (sel == 0xFFFFFFFFu) {   // exact net
                const unsigned short* col = hT + (size_t)(br * 256 + c) * 4096;
                unsigned best = 0xFFFFu;
#pragma unroll 1
                for (int n = 0; n < 4096; n++)
                    if ((int)(mk[n >> 5] << (n & 31)) < 0) { unsigned v = col[n]; if (v < best) best = v; }
                sel = best << 16;
            }
            const float vmin = f16u_to_f(sel >> 16);

            s += (vmax - vmin) * wsv[sl];
        }
#pragma unroll
        for (int off = 32; off; off >>= 1) s += __shfl_xor(s, off);
        if (l == 0)
            out[br * 4096 + e0 + e] = 1.f / (1.f + __expf(-(s + bsc)));
    }
}

// ================================================================ fallback
// Round-13 proven pool (brute-force member-skip scan) for small-ws safety.
#define POOL_STEP(WE, MX0, MX1, MN0, MN1, VX, VY)                          \
    {                                                                      \
        asm("s_add_u32 %[we], %[we], %[we]\n\t"                            \
            "s_cbranch_scc0 Lskip%=\n\t"                                   \
            "v_pk_max_i16 %[mx0], %[mx0], %[vx]\n\t"                       \
            "v_pk_max_i16 %[mx1], %[mx1], %[vy]\n\t"                       \
            "v_pk_min_u16 %[mn0], %[mn0], %[vx]\n\t"                       \
            "v_pk_min_u16 %[mn1], %[mn1], %[vy]\n"                         \
            "Lskip%=:"                                                     \
            : [we] "+s"(WE),                                               \
              [mx0] "+v"(MX0), [mx1] "+v"(MX1),                            \
              [mn0] "+v"(MN0), [mn1] "+v"(MN1)                             \
            : [vx] "v"(VX), [vy] "v"(VY)                                   \
            : "scc");                                                      \
    }

__launch_bounds__(512, 8)
__global__ void k_pool9(const unsigned short* __restrict__ hAll,
                        const unsigned* __restrict__ packed,
                        const float* __restrict__ Wscore,
                        const float* __restrict__ bscore,
                        float* __restrict__ out) {
    __shared__ __align__(16) unsigned bits[4 * 128];
    __shared__ __align__(16) unsigned part[8][4][64][4];

    const int t  = threadIdx.x;
    const int wv = t >> 6;
    const int l  = t & 63;
    const int e0 = blockIdx.x * 4;
    const int br = blockIdx.y;
    const unsigned short* h = hAll + (size_t)br * 4096 * 256;

    if (t < 128) ((uint4*)bits)[t] = ((const uint4*)(packed + e0 * 128))[t];
    __syncthreads();

    unsigned mx0[4], mx1[4], mn0[4], mn1[4];
#pragma unroll
    for (int e = 0; e < 4; e++) {
        mx0[e] = 0x80008000u; mx1[e] = 0x80008000u;
        mn0[e] = 0xFFFFFFFFu; mn1[e] = 0xFFFFFFFFu;
    }

#pragma unroll 1
    for (int ch = 0; ch < 16; ch++) {
        const int w0 = wv * 16 + ch;
        unsigned we0 = (unsigned)__builtin_amdgcn_readfirstlane((int)bits[0 * 128 + w0]);
        unsigned we1 = (unsigned)__builtin_amdgcn_readfirstlane((int)bits[1 * 128 + w0]);
        unsigned we2 = (unsigned)__builtin_amdgcn_readfirstlane((int)bits[2 * 128 + w0]);
        unsigned we3 = (unsigned)__builtin_amdgcn_readfirstlane((int)bits[3 * 128 + w0]);

        const unsigned short* hp = h + (size_t)(wv * 512 + ch * 32) * 256 + 4 * l;
#pragma unroll
        for (int jj = 0; jj < 8; jj++) {
            uint2 v0 = *(const uint2*)(hp + (jj * 4 + 0) * 256);
            uint2 v1 = *(const uint2*)(hp + (jj * 4 + 1) * 256);
            uint2 v2 = *(const uint2*)(hp + (jj * 4 + 2) * 256);
            uint2 v3 = *(const uint2*)(hp + (jj * 4 + 3) * 256);

            POOL_STEP(we0, mx0[0], mx1[0], mn0[0], mn1[0], v0.x, v0.y);
            POOL_STEP(we1, mx0[1], mx1[1], mn0[1], mn1[1], v0.x, v0.y);
            POOL_STEP(we2, mx0[2], mx1[2], mn0[2], mn1[2], v0.x, v0.y);
            POOL_STEP(we3, mx0[3], mx1[3], mn0[3], mn1[3], v0.x, v0.y);
            POOL_STEP(we0, mx0[0], mx1[0], mn0[0], mn1[0], v1.x, v1.y);
            POOL_STEP(we1, mx0[1], mx1[1], mn0[1], mn1[1], v1.x, v1.y);
            POOL_STEP(we2, mx0[2], mx1[2], mn0[2], mn1[2], v1.x, v1.y);
            POOL_STEP(we3, mx0[3], mx1[3], mn0[3], mn1[3], v1.x, v1.y);
            POOL_STEP(we0, mx0[0], mx1[0], mn0[0], mn1[0], v2.x, v2.y);
            POOL_STEP(we1, mx0[1], mx1[1], mn0[1], mn1[1], v2.x, v2.y);
            POOL_STEP(we2, mx0[2], mx1[2], mn0[2], mn1[2], v2.x, v2.y);
            POOL_STEP(we3, mx0[3], mx1[3], mn0[3], mn1[3], v2.x, v2.y);
            POOL_STEP(we0, mx0[0], mx1[0], mn0[0], mn1[0], v3.x, v3.y);
            POOL_STEP(we1, mx0[1], mx1[1], mn0[1], mn1[1], v3.x, v3.y);
            POOL_STEP(we2, mx0[2], mx1[2], mn0[2], mn1[2], v3.x, v3.y);
            POOL_STEP(we3, mx0[3], mx1[3], mn0[3], mn1[3], v3.x, v3.y);
        }
    }

#pragma unroll
    for (int e = 0; e < 4; e++) {
        uint4 p; p.x = mx0[e]; p.y = mx1[e]; p.z = mn0[e]; p.w = mn1[e];
        *(uint4*)&part[wv][e][l][0] = p;
    }
    __syncthreads();

    if (wv < 4) {
        unsigned rmx0 = 0x80008000u, rmx1 = 0x80008000u;
        unsigned rmn0 = 0xFFFFFFFFu, rmn1 = 0xFFFFFFFFu;
#pragma unroll
        for (int w2 = 0; w2 < 8; w2++) {
            uint4 p = *(const uint4*)&part[w2][wv][l][0];
            rmx0 = pkmax_i16(rmx0, p.x);  rmx1 = pkmax_i16(rmx1, p.y);
            rmn0 = pkmin_u16(rmn0, p.z);  rmn1 = pkmin_u16(rmn1, p.w);
        }
        float4 wsv = *(const float4*)(Wscore + 4 * l);
        const float bsc = *bscore;
        float s = (f16u_to_f(rmx0)       - f16u_to_f(rmn0))       * wsv.x
                + (f16u_to_f(rmx0 >> 16) - f16u_to_f(rmn0 >> 16)) * wsv.y
                + (f16u_to_f(rmx1)       - f16u_to_f(rmn1))       * wsv.z
                + (f16u_to_f(rmx1 >> 16) - f16u_to_f(rmn1 >> 16)) * wsv.w;
#pragma unroll
        for (int off = 32; off; off >>= 1) s += __shfl_xor(s, off);
        if (l == 0)
            out[br * 4096 + e0 + wv] = 1.f / (1.f + __expf(-(s + bsc)));
    }
}

// ---------------------------------------------------------------- launch
extern "C" void kernel_launch(void* const* d_in, const int* in_sizes, int n_in,
                              void* d_out, int out_size, void* d_ws, size_t ws_size,
                              hipStream_t stream) {
    const float* pf  = (const float*)d_in[0];
    const float* pm  = (const float*)d_in[1];
    const float* nf  = (const float*)d_in[2];
    const float* nm  = (const float*)d_in[3];
    const int*   msk = (const int*)d_in[4];
    const float* Wsf = (const float*)d_in[5];
    const float* bsf = (const float*)d_in[6];
    const float* Whp = (const float*)d_in[7];
    const float* bhp = (const float*)d_in[8];
    const float* Wsc = (const float*)d_in[9];
    const float* bsc = (const float*)d_in[10];
    float* out = (float*)d_out;

    char* ws = (char*)d_ws;
    const size_t MB = 1024u * 1024u;
    unsigned short* hbuf  = (unsigned short*)(ws);                     // 4 MB: hT (main) or h row-major (fallback)
    unsigned*       pck   = (unsigned*)(ws + 4 * MB);                  // 2 MB  [4096][128]
    unsigned short* Wts   = (unsigned short*)(ws + 6 * MB);            // 128 KB
    unsigned short* Wth   = Wts + 256 * 256;                           // 128 KB
    unsigned*       topkG = (unsigned*)(ws + 6 * MB + 256 * 1024);     // 128 KB [2][64][256]
    unsigned*       botkG = (unsigned*)(ws + 6 * MB + 384 * 1024);     // 128 KB [2][64][256]
    const size_t need = 6 * MB + 512 * 1024;

    k_prepW<<<dim3(4, 4, 2), 256, 0, stream>>>(Wsf, Whp, Wts, Wth);

    if (ws_size >= need) {
        k_gemm_relu<<<dim3(64, 4, 2), 256, 0, stream>>>(pf, pm, nf, nm, Wts, Wth, bsf, bhp, hbuf, 1);
        k_select<<<dim3(256, 2), 512, 0, stream>>>(hbuf, msk, pck, topkG, botkG);
        k_probe<<<dim3(256, 2), 256, 0, stream>>>(topkG, botkG, pck, hbuf, Wsc, bsc, out);
    } else {
        // small-ws fallback: round-13 brute-force pool (needs only ~6.25 MB)
        k_pack<<<2048, 256, 0, stream>>>(msk, pck);
        k_gemm_relu<<<dim3(64, 4, 2), 256, 0, stream>>>(pf, pm, nf, nm, Wts, Wth, bsf, bhp, hbuf, 0);
        k_pool9<<<dim3(1024, 2), 512, 0, stream>>>(hbuf, pck, Wsc, bsc, out);
    }
}

// Round 6
// 174.017 us; speedup vs baseline: 1.0094x; 1.0094x over previous
//
#include <hip/hip_runtime.h>
#include <hip/hip_bf16.h>
#include <hip/hip_fp16.h>

// N=4096 nodes, E=4096 hyperedges, F=256, H=256. All float tensors f32;
// batch_mask int32. out = 8192 f32: [pos_score | neg_score].
//
// R6: probe de-bottleneck (LDS issue-bound at ~9 us):
//   - topkG/botkG layout -> [br][c][64] (column-contiguous). Select's
//     write becomes 256-B wave-contiguous; probe's global fallback reads
//     become contiguous.
//   - probe stages per-column lists column-major in LDS with a 20-dword
//     padded stride (16-B aligned, bases spread across all 32 banks):
//     each 8-probe group = 2 x ds_read_b128 instead of 8 x stride-256 b32
//     (~2x fewer LDS issue cycles on the dominant path).
// k_select unchanged otherwise (R5 radix-select, pinned at the 64-MB
// mask-stream BW floor ~10.5 us -- proven by sort==select in R4/R5).

typedef short bf16x8 __attribute__((ext_vector_type(8)));
typedef float f32x4 __attribute__((ext_vector_type(4)));
typedef short s16x2 __attribute__((ext_vector_type(2)));
typedef unsigned short u16x2 __attribute__((ext_vector_type(2)));

static __device__ __forceinline__ unsigned short f2bf(float f) {
    __hip_bfloat16 b = __float2bfloat16(f);
    return __builtin_bit_cast(unsigned short, b);
}
static __device__ __forceinline__ float f16u_to_f(unsigned u) {
    __half h = __builtin_bit_cast(__half, (unsigned short)(u & 0xffffu));
    return __half2float(h);
}
static __device__ __forceinline__ unsigned pkmax_i16(unsigned a, unsigned b) {
    s16x2 r = __builtin_elementwise_max(__builtin_bit_cast(s16x2, a), __builtin_bit_cast(s16x2, b));
    return __builtin_bit_cast(unsigned, r);
}
static __device__ __forceinline__ unsigned pkmin_u16(unsigned a, unsigned b) {
    u16x2 r = __builtin_elementwise_min(__builtin_bit_cast(u16x2, a), __builtin_bit_cast(u16x2, b));
    return __builtin_bit_cast(unsigned, r);
}

// ---------------------------------------------------------------- tiny W transpose
// Wt[n][k] = bf16(W[k][n]) for both weight matrices. grid (4,4,2), 256 thr.
__global__ void k_prepW(const float* __restrict__ Ws, const float* __restrict__ Wh,
                        unsigned short* __restrict__ Wts, unsigned short* __restrict__ Wth) {
    __shared__ unsigned short tile[64][65];
    const int k0 = blockIdx.x * 64, n0 = blockIdx.y * 64;
    const float* W     = blockIdx.z ? Wh : Ws;
    unsigned short* Wt = blockIdx.z ? Wth : Wts;
    const int t = threadIdx.x;
#pragma unroll
    for (int m = 0; m < 16; m++) {
        int li = t + m * 256; int r = li >> 6, c = li & 63;
        tile[r][c] = f2bf(W[(size_t)(k0 + r) * 256 + n0 + c]);
    }
    __syncthreads();
#pragma unroll
    for (int m = 0; m < 16; m++) {
        int li = t + m * 256; int c2 = li >> 6, r2 = li & 63;
        Wt[(size_t)(n0 + c2) * 256 + k0 + r2] = tile[r2][c2];
    }
}

// ---------------------------------------------------------------- standalone mask pack (fallback path only)
__global__ void k_pack(const int* __restrict__ mask, unsigned* __restrict__ packed) {
    const int w = blockIdx.x * 256 + threadIdx.x;
    const int* p = mask + (size_t)w * 32;
    unsigned word = 0;
#pragma unroll
    for (int j = 0; j < 32; j += 4) {
        int4 m = *(const int4*)(p + j);
        word |= (m.x != 0 ? (1u << (31 - j)) : 0u)
              | (m.y != 0 ? (1u << (30 - j)) : 0u)
              | (m.z != 0 ? (1u << (29 - j)) : 0u)
              | (m.w != 0 ? (1u << (28 - j)) : 0u);
    }
    packed[w] = word;
}

// ---------------------------------------------------------------- GEMM + relu -> f16 h
// tmode=1: write hOut TRANSPOSED as hT[br][c][r]  (main path; feeds k_select)
// tmode=0: write hOut row-major   as h [br][r][c] (fallback path; feeds k_pool9)
__launch_bounds__(256)
__global__ void k_gemm_relu(const float* __restrict__ pXf, const float* __restrict__ pXm,
                            const float* __restrict__ nXf, const float* __restrict__ nXm,
                            const unsigned short* __restrict__ Wts, const unsigned short* __restrict__ Wth,
                            const float* __restrict__ bs,  const float* __restrict__ bh,
                            unsigned short* __restrict__ hOut, int tmode) {
    const int t  = threadIdx.x;
    const int wv = t >> 6;
    const int l  = t & 63;
    const int lm = l & 15;
    const int q  = l >> 4;
    const int bz = blockIdx.z;
    const float* Xf = bz ? nXf : pXf;
    const float* Xm = bz ? nXm : pXm;
    unsigned short* hb = hOut + (size_t)bz * 4096 * 256;

    const int m0 = blockIdx.x * 64 + wv * 16;
    const int n0 = blockIdx.y * 64;

    f32x4 acc[4] = {};
#pragma unroll
    for (int ks = 0; ks < 512; ks += 32) {
        const float* X           = (ks < 256) ? Xf : Xm;
        const unsigned short* Wt = (ks < 256) ? Wts : Wth;
        const int kk = (ks & 255) + q * 8;
        float4 a0 = *(const float4*)(X + (m0 + lm) * 256 + kk);
        float4 a1 = *(const float4*)(X + (m0 + lm) * 256 + kk + 4);
        bf16x8 a;
        a[0] = (short)f2bf(a0.x); a[1] = (short)f2bf(a0.y);
        a[2] = (short)f2bf(a0.z); a[3] = (short)f2bf(a0.w);
        a[4] = (short)f2bf(a1.x); a[5] = (short)f2bf(a1.y);
        a[6] = (short)f2bf(a1.z); a[7] = (short)f2bf(a1.w);
#pragma unroll
        for (int nt = 0; nt < 4; nt++) {
            bf16x8 b = *(const bf16x8*)(Wt + (n0 + nt * 16 + lm) * 256 + kk);
            acc[nt] = __builtin_amdgcn_mfma_f32_16x16x32_bf16(a, b, acc[nt], 0, 0, 0);
        }
    }
    if (tmode) {
#pragma unroll
        for (int nt = 0; nt < 4; nt++) {
            const int c = n0 + nt * 16 + lm;
            const float bsum = bs[c] + bh[c];
            ushort4 v4;
#pragma unroll
            for (int i = 0; i < 4; i++) {
                float v = acc[nt][i] + bsum;
                v = v > 0.f ? v : 0.f;   // relu => h >= +0.0 (u16-monotonic f16 bits)
                ((unsigned short*)&v4)[i] = __builtin_bit_cast(unsigned short, __float2half(v));
            }
            *(ushort4*)(hb + (size_t)c * 4096 + m0 + q * 4) = v4;
        }
    } else {
#pragma unroll
        for (int nt = 0; nt < 4; nt++) {
            const int c = n0 + nt * 16 + lm;
            const float bsum = bs[c] + bh[c];
#pragma unroll
            for (int i = 0; i < 4; i++) {
                const int r = m0 + q * 4 + i;
                float v = acc[nt][i] + bsum;
                v = v > 0.f ? v : 0.f;
                hb[(size_t)r * 256 + c] = __builtin_bit_cast(unsigned short, __float2half(v));
            }
        }
    }
}

// ---------------------------------------------------------------- radix-SELECT top/bot-64 + mask pack
// One block per (col, branch), 512 threads, 8 values/thread (registers).
// 4 nibble rounds refine the exact 64th-value threshold for top (desc) and
// bot (asc) chains simultaneously. Ties at the threshold interchangeable.
// Output layout: topkG/botkG[br][c][64] (column-contiguous; wave writes
// 256-B contiguous). Mask pack fused (kernel is pinned at the 64-MB mask
// stream BW floor). LDS ~9.3 KB. grid (256, 2), block 512.
__launch_bounds__(512)
__global__ void k_select(const unsigned short* __restrict__ hT,
                         const int* __restrict__ mask,
                         unsigned* __restrict__ packed,
                         unsigned* __restrict__ topkG, unsigned* __restrict__ botkG) {
    __shared__ unsigned cbuf[4][512];     // [T-lo, T-hi, B-lo, B-hi] nibble-packed counts
    __shared__ unsigned totals[4][4];     // per-reducer-wave: 8 u16 totals in 4 u32
    __shared__ unsigned selS[4];          // prefT, needT, prefB, needB
    __shared__ unsigned aS[2];            // A_top, A_bot (= #definites)
    __shared__ unsigned wtot2[8][2];      // compaction scan wave totals
    __shared__ unsigned top64[64], bot64[64];

    const int c = blockIdx.x, br = blockIdx.y, t = threadIdx.x;
    const int wv = t >> 6, l = t & 63;
    const unsigned short* src = hT + (size_t)(br * 256 + c) * 4096;

    // mask pack: thread owns packed words 2*gt, 2*gt+1
    const int gt = (br * 256 + c) * 512 + t;
    const int4* mp = (const int4*)(mask + (size_t)gt * 64);
    int4 mr[8];
#pragma unroll
    for (int i = 0; i < 8; i++) mr[i] = mp[i];           // batch 0

    // load 8 consecutive f16 values (u16) into registers
    unsigned vt[8];
    {
        uint4 a = ((const uint4*)src)[t];
        vt[0] = a.x & 0xFFFFu; vt[1] = a.x >> 16;
        vt[2] = a.y & 0xFFFFu; vt[3] = a.y >> 16;
        vt[4] = a.z & 0xFFFFu; vt[5] = a.z >> 16;
        vt[6] = a.w & 0xFFFFu; vt[7] = a.w >> 16;
    }

    auto cvt = [&]() -> unsigned {
        unsigned word = 0;
#pragma unroll
        for (int j2 = 0; j2 < 8; j2++) {
            int4 v = mr[j2];
            const int j = j2 * 4;
            word |= (v.x != 0 ? (1u << (31 - j)) : 0u)
                  | (v.y != 0 ? (1u << (30 - j)) : 0u)
                  | (v.z != 0 ? (1u << (29 - j)) : 0u)
                  | (v.w != 0 ? (1u << (28 - j)) : 0u);
        }
        return word;
    };
    const unsigned pw0 = cvt();                           // batch 0 (arrived under value load)
#pragma unroll
    for (int i = 0; i < 8; i++) mr[i] = mp[8 + i];        // issue batch 1

    // ---- 4 selection rounds (nibbles r=3..0), top & bot chains together
    unsigned prefT = 0, needT = 64, prefB = 0, needB = 64;
#pragma unroll 1
    for (int r = 3; r >= 0; r--) {
        const int shp = (r + 1) * 4, shd = r * 4;
        unsigned cT0 = 0, cT1 = 0, cB0 = 0, cB1 = 0;
#pragma unroll
        for (int m = 0; m < 8; m++) {
            const unsigned hi = vt[m] >> shp;             // r=3: 0 for all (vt<=0xFFFF)
            const unsigned d  = (vt[m] >> shd) & 15u;
            const unsigned inc = 1u << ((d & 7u) * 4);
            const bool lo8 = d < 8u;
            if (hi == prefT) { if (lo8) cT0 += inc; else cT1 += inc; }
            if (hi == prefB) { if (lo8) cB0 += inc; else cB1 += inc; }
        }
        cbuf[0][t] = cT0; cbuf[1][t] = cT1; cbuf[2][t] = cB0; cbuf[3][t] = cB1;
        __syncthreads();

        if (wv < 4) {                                     // reducer wave per count array
            const unsigned* p = cbuf[wv];
            unsigned e0 = 0, e1 = 0;
#pragma unroll
            for (int j = 0; j < 8; j++) {                 // 8 threads' counts -> u8 fields (<=64)
                unsigned x = p[l * 8 + j];
                e0 += x & 0x0F0F0F0Fu;                    // bins 0,2,4,6 (of this half)
                e1 += (x >> 4) & 0x0F0F0F0Fu;             // bins 1,3,5,7
            }
            unsigned w00 = e0 & 0x00FF00FFu, w01 = (e0 >> 8) & 0x00FF00FFu;  // {0,4} {2,6}
            unsigned w10 = e1 & 0x00FF00FFu, w11 = (e1 >> 8) & 0x00FF00FFu;  // {1,5} {3,7}
#pragma unroll
            for (int off = 1; off < 64; off <<= 1) {      // u16 fields, block sums <=4096
                w00 += __shfl_xor(w00, off); w01 += __shfl_xor(w01, off);
                w10 += __shfl_xor(w10, off); w11 += __shfl_xor(w11, off);
            }
            if (l == 0) { totals[wv][0] = w00; totals[wv][1] = w01; totals[wv][2] = w10; totals[wv][3] = w11; }
        }
        __syncthreads();

        if (t == 0) {
            unsigned cnt[16];
            // ---- TOP chain (totals[0]=bins0-7, totals[1]=bins8-15)
            cnt[0]  = totals[0][0] & 0xFFFFu; cnt[4]  = totals[0][0] >> 16;
            cnt[2]  = totals[0][1] & 0xFFFFu; cnt[6]  = totals[0][1] >> 16;
            cnt[1]  = totals[0][2] & 0xFFFFu; cnt[5]  = totals[0][2] >> 16;
            cnt[3]  = totals[0][3] & 0xFFFFu; cnt[7]  = totals[0][3] >> 16;
            cnt[8]  = totals[1][0] & 0xFFFFu; cnt[12] = totals[1][0] >> 16;
            cnt[10] = totals[1][1] & 0xFFFFu; cnt[14] = totals[1][1] >> 16;
            cnt[9]  = totals[1][2] & 0xFFFFu; cnt[13] = totals[1][2] >> 16;
            cnt[11] = totals[1][3] & 0xFFFFu; cnt[15] = totals[1][3] >> 16;
            {
                unsigned S = 0, g = 0, nn = 0; bool done = false;
#pragma unroll
                for (int b = 15; b >= 0; b--) {
                    if (!done) {
                        unsigned cb = cnt[b];
                        if (S + cb >= needT) { g = (unsigned)b; nn = needT - S; done = true; }
                        else S += cb;
                    }
                }
                selS[0] = (prefT << 4) | g; selS[1] = nn;
                if (r == 0) aS[0] = 64u - nn;
            }
            // ---- BOT chain (totals[2], totals[3]), ascending
            cnt[0]  = totals[2][0] & 0xFFFFu; cnt[4]  = totals[2][0] >> 16;
            cnt[2]  = totals[2][1] & 0xFFFFu; cnt[6]  = totals[2][1] >> 16;
            cnt[1]  = totals[2][2] & 0xFFFFu; cnt[5]  = totals[2][2] >> 16;
            cnt[3]  = totals[2][3] & 0xFFFFu; cnt[7]  = totals[2][3] >> 16;
            cnt[8]  = totals[3][0] & 0xFFFFu; cnt[12] = totals[3][0] >> 16;
            cnt[10] = totals[3][1] & 0xFFFFu; cnt[14] = totals[3][1] >> 16;
            cnt[9]  = totals[3][2] & 0xFFFFu; cnt[13] = totals[3][2] >> 16;
            cnt[11] = totals[3][3] & 0xFFFFu; cnt[15] = totals[3][3] >> 16;
            {
                unsigned S = 0, g = 0, nn = 0; bool done = false;
#pragma unroll
                for (int b = 0; b < 16; b++) {
                    if (!done) {
                        unsigned cb = cnt[b];
                        if (S + cb >= needB) { g = (unsigned)b; nn = needB - S; done = true; }
                        else S += cb;
                    }
                }
                selS[2] = (prefB << 4) | g; selS[3] = nn;
                if (r == 0) aS[1] = 64u - nn;
            }
        }
        __syncthreads();
        prefT = selS[0]; needT = selS[1]; prefB = selS[2]; needB = selS[3];
    }

    const unsigned pw1 = cvt();                           // batch 1 (long arrived)

    // ---- compaction: definites (exact) + ties (any 64-A of them)
    const unsigned TvT = prefT, TvB = prefB;
    const unsigned A_T = aS[0], A_B = aS[1];
    unsigned dT = 0, tT = 0, dB = 0, tB = 0;
#pragma unroll
    for (int m = 0; m < 8; m++) {
        dT += vt[m] > TvT;  tT += vt[m] == TvT;
        dB += vt[m] < TvB;  tB += vt[m] == TvB;
    }
    unsigned pkT = dT | (tT << 16), pkB = dB | (tB << 16);
    unsigned sT = pkT, sB = pkB;
#pragma unroll
    for (int off = 1; off < 64; off <<= 1) {              // inclusive wave scan
        unsigned nT = __shfl_up(sT, off), nB = __shfl_up(sB, off);
        if (l >= off) { sT += nT; sB += nB; }
    }
    if (l == 63) { wtot2[wv][0] = sT; wtot2[wv][1] = sB; }
    __syncthreads();
    unsigned exT = sT - pkT, exB = sB - pkB;              // exclusive within wave
#pragma unroll
    for (int w = 0; w < 7; w++)
        if (w < wv) { exT += wtot2[w][0]; exB += wtot2[w][1]; }
    unsigned posDT = exT & 0xFFFFu, posTT = exT >> 16;
    unsigned posDB = exB & 0xFFFFu, posTB = exB >> 16;
#pragma unroll
    for (int m = 0; m < 8; m++) {
        const unsigned key = (vt[m] << 16) | (unsigned)(t * 8 + m);
        if (vt[m] > TvT)        top64[posDT++] = key;
        else if (vt[m] == TvT) { unsigned s2 = A_T + posTT++; if (s2 < 64u) top64[s2] = key; }
        if (vt[m] < TvB)        bot64[posDB++] = key;
        else if (vt[m] == TvB) { unsigned s2 = A_B + posTB++; if (s2 < 64u) bot64[s2] = key; }
    }
    __syncthreads();

    // ---- one-wave bitonic sort of each 64-list (full 32-bit key)
    if (wv < 2) {
        const unsigned flip = (wv == 0) ? 0xFFFFFFFFu : 0u;   // top: sort ~key asc == key desc
        unsigned v = ((wv == 0) ? top64[l] : bot64[l]) ^ flip;
#pragma unroll
        for (unsigned k2 = 2; k2 <= 64; k2 <<= 1) {
#pragma unroll
            for (unsigned j = k2 >> 1; j > 0; j >>= 1) {
                unsigned o = __shfl_xor(v, (int)j);
                const bool keepMin = (((unsigned)l & j) == 0) == (((unsigned)l & k2) == 0);
                const unsigned mn = v < o ? v : o, mx = v < o ? o : v;
                v = keepMin ? mn : mx;
            }
        }
        v ^= flip;
        // column-contiguous layout [br][c][64]: wave writes 256 B contiguous
        if (wv == 0) topkG[((size_t)(br * 256 + c)) * 64 + l] = v;
        else         botkG[((size_t)(br * 256 + c)) * 64 + l] = v;
    }

    *(uint2*)(packed + (size_t)gt * 2) = make_uint2(pw0, pw1);
}

// ---------------------------------------------------------------- probe + score
// Block: 16 edges x one branch; 4 waves x 4 edges. Lane l covers cols
// c = l + 64*sl. Per-column probe lists staged COLUMN-MAJOR (20-dword
// padded stride: 16-B aligned, column bases spread over all 32 banks):
// each 8-probe group = 2 x ds_read_b128 (was 8 x stride-256 b32).
// Depth 0..15 from LDS; 16..63 from global [c][64] (contiguous); beyond
// (P=2^-64) exact hT column scan. LDS 48 KB. grid (256, 2), block 256.
__launch_bounds__(256)
__global__ void k_probe(const unsigned* __restrict__ topkG,
                        const unsigned* __restrict__ botkG,
                        const unsigned* __restrict__ packed,
                        const unsigned short* __restrict__ hT,
                        const float* __restrict__ Wscore,
                        const float* __restrict__ bscore,
                        float* __restrict__ out) {
    __shared__ __align__(16) unsigned topkL[256 * 20];   // col-major 16 keys + 4 pad = 20 KB
    __shared__ __align__(16) unsigned botkL[256 * 20];   // 20 KB
    __shared__ __align__(16) unsigned bitsL[16 * 128];   // 8 KB

    const int t  = threadIdx.x;
    const int wv = t >> 6;
    const int l  = t & 63;
    const int e0 = blockIdx.x * 16;
    const int br = blockIdx.y;

    {
        const uint4* ts  = (const uint4*)(topkG + (size_t)br * 256 * 64);
        const uint4* bs2 = (const uint4*)(botkG + (size_t)br * 256 * 64);
#pragma unroll
        for (int m = 0; m < 4; m++) {
            const int i = t + m * 256;          // 0..1023
            const int col = i >> 2, j = i & 3;  // first 4 quads (16 keys) of each column
            ((uint4*)topkL)[col * 5 + j] = ts[col * 16 + j];
            ((uint4*)botkL)[col * 5 + j] = bs2[col * 16 + j];
        }
        ((uint4*)bitsL)[t]       = ((const uint4*)(packed + e0 * 128))[t];
        ((uint4*)bitsL)[t + 256] = ((const uint4*)(packed + e0 * 128))[t + 256];
    }
    __syncthreads();

    const float bsc = *bscore;
    float wsv[4];
#pragma unroll
    for (int sl = 0; sl < 4; sl++) wsv[sl] = Wscore[l + 64 * sl];

#pragma unroll 1
    for (int k = 0; k < 4; k++) {
        const int e = wv * 4 + k;
        const unsigned* mk = &bitsL[e * 128];
        float s = 0.f;
#pragma unroll
        for (int sl = 0; sl < 4; sl++) {
            const int c = l + 64 * sl;
            const unsigned* tcol = topkL + c * 20;
            const unsigned* bcol = botkL + c * 20;

            // ---- MAX: first member in descending order
            unsigned sel = 0xFFFFFFFFu;   // > any real key (value<=0x7C00)
#pragma unroll 1
            for (int g = 0; g < 2; g++) {
                uint4 q0 = *(const uint4*)(tcol + g * 8);
                uint4 q1 = *(const uint4*)(tcol + g * 8 + 4);
                unsigned kk[8] = {q0.x, q0.y, q0.z, q0.w, q1.x, q1.y, q1.z, q1.w};
                int ss[8];
#pragma unroll
                for (int j = 0; j < 8; j++)
                    ss[j] = (int)(mk[(kk[j] & 4095u) >> 5] << (kk[j] & 31u));
                unsigned fnd = 0xFFFFFFFFu;
#pragma unroll
                for (int j = 7; j >= 0; j--) if (ss[j] < 0) fnd = kk[j];
                if (fnd != 0xFFFFFFFFu) { sel = fnd; break; }
            }
            if (sel == 0xFFFFFFFFu) {
                const unsigned* tg = topkG + ((size_t)(br * 256 + c)) * 64;
#pragma unroll 1
                for (int p = 16; p < 64; p++) {
                    unsigned key = tg[p];
                    if ((int)(mk[(key & 4095u) >> 5] << (key & 31u)) < 0) { sel = key; break; }
                }
            }
            if (sel == 0xFFFFFFFFu) {   // exact net (P=2^-64; edge nonempty via diagonal)
                const unsigned short* col = hT + (size_t)(br * 256 + c) * 4096;
                unsigned best = 0;
#pragma unroll 1
                for (int n = 0; n < 4096; n++)
                    if ((int)(mk[n >> 5] << (n & 31)) < 0) { unsigned v = col[n]; if (v > best) best = v; }
                sel = best << 16;
            }
            const float vmax = f16u_to_f(sel >> 16);

            // ---- MIN: first member in ascending order
            sel = 0xFFFFFFFFu;
#pragma unroll 1
            for (int g = 0; g < 2; g++) {
                uint4 q0 = *(const uint4*)(bcol + g * 8);
                uint4 q1 = *(const uint4*)(bcol + g * 8 + 4);
                unsigned kk[8] = {q0.x, q0.y, q0.z, q0.w, q1.x, q1.y, q1.z, q1.w};
                int ss[8];
#pragma unroll
                for (int j = 0; j < 8; j++)
                    ss[j] = (int)(mk[(kk[j] & 4095u) >> 5] << (kk[j] & 31u));
                unsigned fnd = 0xFFFFFFFFu;
#pragma unroll
                for (int j = 7; j >= 0; j--) if (ss[j] < 0) fnd = kk[j];
                if (fnd != 0xFFFFFFFFu) { sel = fnd; break; }
            }
            if (sel == 0xFFFFFFFFu) {
                const unsigned* bg = botkG + ((size_t)(br * 256 + c)) * 64;
#pragma unroll 1
                for (int p = 16; p < 64; p++) {
                    unsigned key = bg[p];
                    if ((int)(mk[(key & 4095u) >> 5] << (key & 31u)) < 0) { sel = key; break; }
                }
            }
            if (sel == 0xFFFFFFFFu) {   // exact net
                const unsigned short* col = hT + (size_t)(br * 256 + c) * 4096;
                unsigned best = 0xFFFFu;
#pragma unroll 1
                for (int n = 0; n < 4096; n++)
                    if ((int)(mk[n >> 5] << (n & 31)) < 0) { unsigned v = col[n]; if (v < best) best = v; }
                sel = best << 16;
            }
            const float vmin = f16u_to_f(sel >> 16);

            s += (vmax - vmin) * wsv[sl];
        }
#pragma unroll
        for (int off = 32; off; off >>= 1) s += __shfl_xor(s, off);
        if (l == 0)
            out[br * 4096 + e0 + e] = 1.f / (1.f + __expf(-(s + bsc)));
    }
}

// ================================================================ fallback
// Round-13 proven pool (brute-force member-skip scan) for small-ws safety.
#define POOL_STEP(WE, MX0, MX1, MN0, MN1, VX, VY)                          \
    {                                                                      \
        asm("s_add_u32 %[we], %[we], %[we]\n\t"                            \
            "s_cbranch_scc0 Lskip%=\n\t"                                   \
            "v_pk_max_i16 %[mx0], %[mx0], %[vx]\n\t"                       \
            "v_pk_max_i16 %[mx1], %[mx1], %[vy]\n\t"                       \
            "v_pk_min_u16 %[mn0], %[mn0], %[vx]\n\t"                       \
            "v_pk_min_u16 %[mn1], %[mn1], %[vy]\n"                         \
            "Lskip%=:"                                                     \
            : [we] "+s"(WE),                                               \
              [mx0] "+v"(MX0), [mx1] "+v"(MX1),                            \
              [mn0] "+v"(MN0), [mn1] "+v"(MN1)                             \
            : [vx] "v"(VX), [vy] "v"(VY)                                   \
            : "scc");                                                      \
    }

__launch_bounds__(512, 8)
__global__ void k_pool9(const unsigned short* __restrict__ hAll,
                        const unsigned* __restrict__ packed,
                        const float* __restrict__ Wscore,
                        const float* __restrict__ bscore,
                        float* __restrict__ out) {
    __shared__ __align__(16) unsigned bits[4 * 128];
    __shared__ __align__(16) unsigned part[8][4][64][4];

    const int t  = threadIdx.x;
    const int wv = t >> 6;
    const int l  = t & 63;
    const int e0 = blockIdx.x * 4;
    const int br = blockIdx.y;
    const unsigned short* h = hAll + (size_t)br * 4096 * 256;

    if (t < 128) ((uint4*)bits)[t] = ((const uint4*)(packed + e0 * 128))[t];
    __syncthreads();

    unsigned mx0[4], mx1[4], mn0[4], mn1[4];
#pragma unroll
    for (int e = 0; e < 4; e++) {
        mx0[e] = 0x80008000u; mx1[e] = 0x80008000u;
        mn0[e] = 0xFFFFFFFFu; mn1[e] = 0xFFFFFFFFu;
    }

#pragma unroll 1
    for (int ch = 0; ch < 16; ch++) {
        const int w0 = wv * 16 + ch;
        unsigned we0 = (unsigned)__builtin_amdgcn_readfirstlane((int)bits[0 * 128 + w0]);
        unsigned we1 = (unsigned)__builtin_amdgcn_readfirstlane((int)bits[1 * 128 + w0]);
        unsigned we2 = (unsigned)__builtin_amdgcn_readfirstlane((int)bits[2 * 128 + w0]);
        unsigned we3 = (unsigned)__builtin_amdgcn_readfirstlane((int)bits[3 * 128 + w0]);

        const unsigned short* hp = h + (size_t)(wv * 512 + ch * 32) * 256 + 4 * l;
#pragma unroll
        for (int jj = 0; jj < 8; jj++) {
            uint2 v0 = *(const uint2*)(hp + (jj * 4 + 0) * 256);
            uint2 v1 = *(const uint2*)(hp + (jj * 4 + 1) * 256);
            uint2 v2 = *(const uint2*)(hp + (jj * 4 + 2) * 256);
            uint2 v3 = *(const uint2*)(hp + (jj * 4 + 3) * 256);

            POOL_STEP(we0, mx0[0], mx1[0], mn0[0], mn1[0], v0.x, v0.y);
            POOL_STEP(we1, mx0[1], mx1[1], mn0[1], mn1[1], v0.x, v0.y);
            POOL_STEP(we2, mx0[2], mx1[2], mn0[2], mn1[2], v0.x, v0.y);
            POOL_STEP(we3, mx0[3], mx1[3], mn0[3], mn1[3], v0.x, v0.y);
            POOL_STEP(we0, mx0[0], mx1[0], mn0[0], mn1[0], v1.x, v1.y);
            POOL_STEP(we1, mx0[1], mx1[1], mn0[1], mn1[1], v1.x, v1.y);
            POOL_STEP(we2, mx0[2], mx1[2], mn0[2], mn1[2], v1.x, v1.y);
            POOL_STEP(we3, mx0[3], mx1[3], mn0[3], mn1[3], v1.x, v1.y);
            POOL_STEP(we0, mx0[0], mx1[0], mn0[0], mn1[0], v2.x, v2.y);
            POOL_STEP(we1, mx0[1], mx1[1], mn0[1], mn1[1], v2.x, v2.y);
            POOL_STEP(we2, mx0[2], mx1[2], mn0[2], mn1[2], v2.x, v2.y);
            POOL_STEP(we3, mx0[3], mx1[3], mn0[3], mn1[3], v2.x, v2.y);
            POOL_STEP(we0, mx0[0], mx1[0], mn0[0], mn1[0], v3.x, v3.y);
            POOL_STEP(we1, mx0[1], mx1[1], mn0[1], mn1[1], v3.x, v3.y);
            POOL_STEP(we2, mx0[2], mx1[2], mn0[2], mn1[2], v3.x, v3.y);
            POOL_STEP(we3, mx0[3], mx1[3], mn0[3], mn1[3], v3.x, v3.y);
        }
    }

#pragma unroll
    for (int e = 0; e < 4; e++) {
        uint4 p; p.x = mx0[e]; p.y = mx1[e]; p.z = mn0[e]; p.w = mn1[e];
        *(uint4*)&part[wv][e][l][0] = p;
    }
    __syncthreads();

    if (wv < 4) {
        unsigned rmx0 = 0x80008000u, rmx1 = 0x80008000u;
        unsigned rmn0 = 0xFFFFFFFFu, rmn1 = 0xFFFFFFFFu;
#pragma unroll
        for (int w2 = 0; w2 < 8; w2++) {
            uint4 p = *(const uint4*)&part[w2][wv][l][0];
            rmx0 = pkmax_i16(rmx0, p.x);  rmx1 = pkmax_i16(rmx1, p.y);
            rmn0 = pkmin_u16(rmn0, p.z);  rmn1 = pkmin_u16(rmn1, p.w);
        }
        float4 wsv = *(const float4*)(Wscore + 4 * l);
        const float bsc = *bscore;
        float s = (f16u_to_f(rmx0)       - f16u_to_f(rmn0))       * wsv.x
                + (f16u_to_f(rmx0 >> 16) - f16u_to_f(rmn0 >> 16)) * wsv.y
                + (f16u_to_f(rmx1)       - f16u_to_f(rmn1))       * wsv.z
                + (f16u_to_f(rmx1 >> 16) - f16u_to_f(rmn1 >> 16)) * wsv.w;
#pragma unroll
        for (int off = 32; off; off >>= 1) s += __shfl_xor(s, off);
        if (l == 0)
            out[br * 4096 + e0 + wv] = 1.f / (1.f + __expf(-(s + bsc)));
    }
}

// ---------------------------------------------------------------- launch
extern "C" void kernel_launch(void* const* d_in, const int* in_sizes, int n_in,
                              void* d_out, int out_size, void* d_ws, size_t ws_size,
                              hipStream_t stream) {
    const float* pf  = (const float*)d_in[0];
    const float* pm  = (const float*)d_in[1];
    const float* nf  = (const float*)d_in[2];
    const float* nm  = (const float*)d_in[3];
    const int*   msk = (const int*)d_in[4];
    const float* Wsf = (const float*)d_in[5];
    const float* bsf = (const float*)d_in[6];
    const float* Whp = (const float*)d_in[7];
    const float* bhp = (const float*)d_in[8];
    const float* Wsc = (const float*)d_in[9];
    const float* bsc = (const float*)d_in[10];
    float* out = (float*)d_out;

    char* ws = (char*)d_ws;
    const size_t MB = 1024u * 1024u;
    unsigned short* hbuf  = (unsigned short*)(ws);                     // 4 MB: hT (main) or h row-major (fallback)
    unsigned*       pck   = (unsigned*)(ws + 4 * MB);                  // 2 MB  [4096][128]
    unsigned short* Wts   = (unsigned short*)(ws + 6 * MB);            // 128 KB
    unsigned short* Wth   = Wts + 256 * 256;                           // 128 KB
    unsigned*       topkG = (unsigned*)(ws + 6 * MB + 256 * 1024);     // 128 KB [2][256][64]
    unsigned*       botkG = (unsigned*)(ws + 6 * MB + 384 * 1024);     // 128 KB [2][256][64]
    const size_t need = 6 * MB + 512 * 1024;

    k_prepW<<<dim3(4, 4, 2), 256, 0, stream>>>(Wsf, Whp, Wts, Wth);

    if (ws_size >= need) {
        k_gemm_relu<<<dim3(64, 4, 2), 256, 0, stream>>>(pf, pm, nf, nm, Wts, Wth, bsf, bhp, hbuf, 1);
        k_select<<<dim3(256, 2), 512, 0, stream>>>(hbuf, msk, pck, topkG, botkG);
        k_probe<<<dim3(256, 2), 256, 0, stream>>>(topkG, botkG, pck, hbuf, Wsc, bsc, out);
    } else {
        // small-ws fallback: round-13 brute-force pool (needs only ~6.25 MB)
        k_pack<<<2048, 256, 0, stream>>>(msk, pck);
        k_gemm_relu<<<dim3(64, 4, 2), 256, 0, stream>>>(pf, pm, nf, nm, Wts, Wth, bsf, bhp, hbuf, 0);
        k_pool9<<<dim3(1024, 2), 512, 0, stream>>>(hbuf, pck, Wsc, bsc, out);
    }
}